// Round 3
// baseline (1475.654 us; speedup 1.0000x reference)
//
#include <hip/hip_runtime.h>

typedef unsigned short u16;
typedef __bf16 bf16x8 __attribute__((ext_vector_type(8)));
typedef unsigned short u16x8 __attribute__((ext_vector_type(8)));
typedef unsigned short u16x4 __attribute__((ext_vector_type(4)));
typedef float f32x4 __attribute__((ext_vector_type(4)));

#define K_DIM 2048

// async global->LDS, 16B per lane; lds ptr must be wave-uniform base (+lane*16 in HW)
#define GLL16(g, l) __builtin_amdgcn_global_load_lds( \
    (const __attribute__((address_space(1))) void*)(g), \
    (__attribute__((address_space(3))) void*)(l), 16, 0, 0)

#define SB()  __builtin_amdgcn_sched_barrier(0)
#define BAR() __builtin_amdgcn_s_barrier()
// scheduling-only fences: NO ":::memory" anywhere in the hot loop (R1's fatal flaw --
// memory clobbers made the legalizer drain vmcnt(0) at every phase).
#define PH_PRE()  do { SB(); BAR(); SB(); } while (0)
#define PH_END()  do { SB(); BAR(); SB(); } while (0)
#define PH_END_V4() do { SB(); asm volatile("s_waitcnt vmcnt(4)"); SB(); BAR(); SB(); } while (0)
#define MFMA_(av, bv, cc) (cc) = __builtin_amdgcn_mfma_f32_16x16x32_bf16((av), (bv), (cc), 0, 0, 0)

__device__ __forceinline__ u16 f2bf(float f) {
    unsigned int u = __builtin_bit_cast(unsigned int, f);
    u = (u + 0x7fffu + ((u >> 16) & 1u)) >> 16;   // RNE
    return (u16)u;
}
__device__ __forceinline__ float bf2f(u16 h) {
    unsigned int u = ((unsigned int)h) << 16;
    return __builtin_bit_cast(float, u);
}
__device__ __forceinline__ float softplus_f(float v) {
    return fmaxf(v, 0.0f) + log1pf(expf(-fabsf(v)));
}

// ---------------- pack f32 -> bf16, 4 elems/thread ----------------
__global__ void pack_kernel(const float* __restrict__ src, u16* __restrict__ dst, int n4) {
    int i = blockIdx.x * blockDim.x + threadIdx.x;
    if (i >= n4) return;
    float4 v = ((const float4*)src)[i];
    u16x4 o;
    o[0] = f2bf(v.x); o[1] = f2bf(v.y); o[2] = f2bf(v.z); o[3] = f2bf(v.w);
    ((u16x4*)dst)[i] = o;
}

// ---- pack all 4 weight matrices in one launch: grid.y selects source ----
__global__ void pack4_kernel(const float* __restrict__ s0, const float* __restrict__ s1,
                             const float* __restrict__ s2, const float* __restrict__ s3,
                             u16* __restrict__ dst) {
    int i = blockIdx.x * blockDim.x + threadIdx.x;   // 0 .. 1048575 (float4 units)
    const float* src = (blockIdx.y == 0) ? s0 : (blockIdx.y == 1) ? s1
                     : (blockIdx.y == 2) ? s2 : s3;
    float4 v = ((const float4*)src)[i];
    u16x4 o;
    o[0] = f2bf(v.x); o[1] = f2bf(v.y); o[2] = f2bf(v.z); o[3] = f2bf(v.w);
    ((u16x4*)(dst + (size_t)blockIdx.y * 4194304))[i] = o;
}

// ---------------- fused GEMM: C = A * B^T, 256x256 tile, BK=64, 8-phase counted-vmcnt ----------------
// LDS per matrix: [2 buf][2 kslice][16 groups of 16 rows][64 chunks of 16B], XOR/add swizzle:
// chunk (row r, q) at in-group pos (r&15)*4 + ((q + ((r&15)>>1))&3)  -> 0-conflict ds_read_b128.
// Phase schedule (2 K-tiles/iter; buf0 = tile 2i computed ph1-4, buf1 = tile 2i+1 ph5-8):
//   ph1: read a0-3,b0-1(buf0); stage A-half0 -> buf1;      MFMA a03 x b01
//   ph2: read b2-3(buf0);      stage A-half1 -> buf1;      MFMA a03 x b23
//   ph3: read a4-7(buf0);      stage B-half0 -> buf0_next; MFMA a47 x b23
//   ph4:                       stage B-half1 -> buf0_next; MFMA a47 x b01; vmcnt(4)
//   ph5-8: same with buf roles swapped; vmcnt(4) at ph8.
// vmcnt(4) at ph4 drains ph1/ph2 loads (buf1-A) before ph5 reads buf1; at ph8 drains
// ph3-6 loads (buf0 B then A) before next ph1 reads buf0. Barrier after the vmcnt makes
// each wave's drain visible to all. All staged regions' last LDS read is >=1 barrier earlier.
__global__ __launch_bounds__(512, 2) void gemm_fused(
    const u16* __restrict__ xb, const u16* __restrict__ wb,
    u16* __restrict__ qb, u16* __restrict__ kb,
    u16* __restrict__ sqb, u16* __restrict__ skb)
{
    __shared__ __align__(16) u16 Als[32768];   // 2 bufs x 16384 u16 (32KB each)
    __shared__ __align__(16) u16 Bls[32768];
    __shared__ float ss[512];

    const int tid  = threadIdx.x;
    const int lane = tid & 63;
    const int wave = tid >> 6;
    const int wm   = wave >> 2;     // 2 waves in M
    const int wn   = wave & 3;      // 4 waves in N
    const int gm0  = blockIdx.y * 256;
    const int gn0  = blockIdx.x * 256;

    // staging geometry: load l covers (kslice s=l>>1, row-group g=(l&1)*8+wave);
    // lane -> row g*16+(lane>>2); slot pos j=lane&3 receives source chunk q=(j-(row&15)>>1... )&3.
    const int q8 = (((lane & 3) - ((lane >> 3) & 3)) & 3) * 8;
    const int sB = wave * 512;                          // LDS u16 offset base; + l*4096
    const u16* pa0 = xb + (size_t)(gm0 + wave * 16 + (lane >> 2)) * K_DIM + q8;
    const u16* pb0 = wb + (size_t)(gn0 + wave * 16 + (lane >> 2)) * K_DIM + q8;
    const size_t SRC1 = (size_t)128 * K_DIM;            // l=1: +128 rows
    // l=2: +32 cols (kslice 1); l=3: +128 rows +32 cols

    // read side: lane holds row mr=lane&15 of a group, k-chunk lane>>4 at swizzled pos
    const int mr  = lane & 15;
    const int srd = ((lane >> 4) + (mr >> 1)) & 3;
    const int fro = mr * 32 + srd * 8;
    const int aRB = wm * 8 * 512 + fro;    // A groups wm*8 + i
    const int bRB = wn * 4 * 512 + fro;    // B groups wn*4 + j

    f32x4 acc[8][4] = {};

#define LDA(buf, i, ks) __builtin_bit_cast(bf16x8, *(const u16x8*)&Als[(buf)*16384 + (ks)*8192 + aRB + (i)*512])
#define LDB(buf, j, ks) __builtin_bit_cast(bf16x8, *(const u16x8*)&Bls[(buf)*16384 + (ks)*8192 + bRB + (j)*512])
#define STAGE_A(coff, dbase) do { \
    GLL16(pa0 + (coff),          &Als[(dbase) + sB]); \
    GLL16(pa0 + (coff) + SRC1,   &Als[(dbase) + sB + 4096]); \
    GLL16(pa0 + (coff) + 32,     &Als[(dbase) + sB + 8192]); \
    GLL16(pa0 + (coff) + SRC1 + 32, &Als[(dbase) + sB + 12288]); } while (0)
#define STAGE_B(coff, dbase) do { \
    GLL16(pb0 + (coff),          &Bls[(dbase) + sB]); \
    GLL16(pb0 + (coff) + SRC1,   &Bls[(dbase) + sB + 4096]); \
    GLL16(pb0 + (coff) + 32,     &Bls[(dbase) + sB + 8192]); \
    GLL16(pb0 + (coff) + SRC1 + 32, &Bls[(dbase) + sB + 12288]); } while (0)
// half-stages: 2 loads each
#define STAGE_A_H0(coff, dbase) do { \
    GLL16(pa0 + (coff),        &Als[(dbase) + sB]); \
    GLL16(pa0 + (coff) + SRC1, &Als[(dbase) + sB + 4096]); } while (0)
#define STAGE_A_H1(coff, dbase) do { \
    GLL16(pa0 + (coff) + 32,        &Als[(dbase) + sB + 8192]); \
    GLL16(pa0 + (coff) + SRC1 + 32, &Als[(dbase) + sB + 12288]); } while (0)
#define STAGE_B_H0(coff, dbase) do { \
    GLL16(pb0 + (coff),        &Bls[(dbase) + sB]); \
    GLL16(pb0 + (coff) + SRC1, &Bls[(dbase) + sB + 4096]); } while (0)
#define STAGE_B_H1(coff, dbase) do { \
    GLL16(pb0 + (coff) + 32,        &Bls[(dbase) + sB + 8192]); \
    GLL16(pb0 + (coff) + SRC1 + 32, &Bls[(dbase) + sB + 12288]); } while (0)

    // prologue: tile0 A,B -> buf0; tile1 B -> buf1; full drain
    STAGE_A(0, 0);
    STAGE_B(0, 0);
    STAGE_B(64, 16384);
    __syncthreads();

    for (int it = 0; it < 16; ++it) {
        bf16x8 aF[4][2], b01[2][2], b23[2][2];

        // ======== ph1: a03,b01(buf0); stage A-h0 -> buf1; a03 x b01 ========
#pragma unroll
        for (int i = 0; i < 4; ++i) { aF[i][0] = LDA(0, i, 0); aF[i][1] = LDA(0, i, 1); }
#pragma unroll
        for (int j = 0; j < 2; ++j) { b01[j][0] = LDB(0, j, 0); b01[j][1] = LDB(0, j, 1); }
        STAGE_A_H0(64, 16384);
        PH_PRE();
        __builtin_amdgcn_s_setprio(1);
#pragma unroll
        for (int i = 0; i < 4; ++i) MFMA_(aF[i][0], b01[0][0], acc[i][0]);
#pragma unroll
        for (int i = 0; i < 4; ++i) MFMA_(aF[i][0], b01[1][0], acc[i][1]);
#pragma unroll
        for (int i = 0; i < 4; ++i) MFMA_(aF[i][1], b01[0][1], acc[i][0]);
#pragma unroll
        for (int i = 0; i < 4; ++i) MFMA_(aF[i][1], b01[1][1], acc[i][1]);
        __builtin_amdgcn_s_setprio(0);
        PH_END();

        // ======== ph2: b23(buf0); stage A-h1 -> buf1; a03 x b23 ========
#pragma unroll
        for (int j = 0; j < 2; ++j) { b23[j][0] = LDB(0, j + 2, 0); b23[j][1] = LDB(0, j + 2, 1); }
        STAGE_A_H1(64, 16384);
        PH_PRE();
        __builtin_amdgcn_s_setprio(1);
#pragma unroll
        for (int i = 0; i < 4; ++i) MFMA_(aF[i][0], b23[0][0], acc[i][2]);
#pragma unroll
        for (int i = 0; i < 4; ++i) MFMA_(aF[i][0], b23[1][0], acc[i][3]);
#pragma unroll
        for (int i = 0; i < 4; ++i) MFMA_(aF[i][1], b23[0][1], acc[i][2]);
#pragma unroll
        for (int i = 0; i < 4; ++i) MFMA_(aF[i][1], b23[1][1], acc[i][3]);
        __builtin_amdgcn_s_setprio(0);
        PH_END();

        // ======== ph3: a47(buf0); stage B-h0 -> buf0(next); a47 x b23 ========
#pragma unroll
        for (int i = 0; i < 4; ++i) { aF[i][0] = LDA(0, i + 4, 0); aF[i][1] = LDA(0, i + 4, 1); }
        STAGE_B_H0(128, 0);
        PH_PRE();
        __builtin_amdgcn_s_setprio(1);
#pragma unroll
        for (int i = 0; i < 4; ++i) MFMA_(aF[i][0], b23[0][0], acc[4 + i][2]);
#pragma unroll
        for (int i = 0; i < 4; ++i) MFMA_(aF[i][0], b23[1][0], acc[4 + i][3]);
#pragma unroll
        for (int i = 0; i < 4; ++i) MFMA_(aF[i][1], b23[0][1], acc[4 + i][2]);
#pragma unroll
        for (int i = 0; i < 4; ++i) MFMA_(aF[i][1], b23[1][1], acc[4 + i][3]);
        __builtin_amdgcn_s_setprio(0);
        PH_END();

        // ======== ph4: stage B-h1 -> buf0(next); a47 x b01; vmcnt(4) ========
        STAGE_B_H1(128, 0);
        PH_PRE();
        __builtin_amdgcn_s_setprio(1);
#pragma unroll
        for (int i = 0; i < 4; ++i) MFMA_(aF[i][0], b01[0][0], acc[4 + i][0]);
#pragma unroll
        for (int i = 0; i < 4; ++i) MFMA_(aF[i][0], b01[1][0], acc[4 + i][1]);
#pragma unroll
        for (int i = 0; i < 4; ++i) MFMA_(aF[i][1], b01[0][1], acc[4 + i][0]);
#pragma unroll
        for (int i = 0; i < 4; ++i) MFMA_(aF[i][1], b01[1][1], acc[4 + i][1]);
        __builtin_amdgcn_s_setprio(0);
        PH_END_V4();

        // ======== ph5: a03,b01(buf1); stage A-h0 -> buf0(next); a03 x b01 ========
#pragma unroll
        for (int i = 0; i < 4; ++i) { aF[i][0] = LDA(1, i, 0); aF[i][1] = LDA(1, i, 1); }
#pragma unroll
        for (int j = 0; j < 2; ++j) { b01[j][0] = LDB(1, j, 0); b01[j][1] = LDB(1, j, 1); }
        STAGE_A_H0(128, 0);
        PH_PRE();
        __builtin_amdgcn_s_setprio(1);
#pragma unroll
        for (int i = 0; i < 4; ++i) MFMA_(aF[i][0], b01[0][0], acc[i][0]);
#pragma unroll
        for (int i = 0; i < 4; ++i) MFMA_(aF[i][0], b01[1][0], acc[i][1]);
#pragma unroll
        for (int i = 0; i < 4; ++i) MFMA_(aF[i][1], b01[0][1], acc[i][0]);
#pragma unroll
        for (int i = 0; i < 4; ++i) MFMA_(aF[i][1], b01[1][1], acc[i][1]);
        __builtin_amdgcn_s_setprio(0);
        PH_END();

        // ======== ph6: b23(buf1); stage A-h1 -> buf0(next); a03 x b23 ========
#pragma unroll
        for (int j = 0; j < 2; ++j) { b23[j][0] = LDB(1, j + 2, 0); b23[j][1] = LDB(1, j + 2, 1); }
        STAGE_A_H1(128, 0);
        PH_PRE();
        __builtin_amdgcn_s_setprio(1);
#pragma unroll
        for (int i = 0; i < 4; ++i) MFMA_(aF[i][0], b23[0][0], acc[i][2]);
#pragma unroll
        for (int i = 0; i < 4; ++i) MFMA_(aF[i][0], b23[1][0], acc[i][3]);
#pragma unroll
        for (int i = 0; i < 4; ++i) MFMA_(aF[i][1], b23[0][1], acc[i][2]);
#pragma unroll
        for (int i = 0; i < 4; ++i) MFMA_(aF[i][1], b23[1][1], acc[i][3]);
        __builtin_amdgcn_s_setprio(0);
        PH_END();

        // ======== ph7: a47(buf1); stage B-h0 -> buf1(next); a47 x b23 ========
#pragma unroll
        for (int i = 0; i < 4; ++i) { aF[i][0] = LDA(1, i + 4, 0); aF[i][1] = LDA(1, i + 4, 1); }
        STAGE_B_H0(192, 16384);
        PH_PRE();
        __builtin_amdgcn_s_setprio(1);
#pragma unroll
        for (int i = 0; i < 4; ++i) MFMA_(aF[i][0], b23[0][0], acc[4 + i][2]);
#pragma unroll
        for (int i = 0; i < 4; ++i) MFMA_(aF[i][0], b23[1][0], acc[4 + i][3]);
#pragma unroll
        for (int i = 0; i < 4; ++i) MFMA_(aF[i][1], b23[0][1], acc[4 + i][2]);
#pragma unroll
        for (int i = 0; i < 4; ++i) MFMA_(aF[i][1], b23[1][1], acc[4 + i][3]);
        __builtin_amdgcn_s_setprio(0);
        PH_END();

        // ======== ph8: stage B-h1 -> buf1(next); a47 x b01; vmcnt(4) ========
        STAGE_B_H1(192, 16384);
        PH_PRE();
        __builtin_amdgcn_s_setprio(1);
#pragma unroll
        for (int i = 0; i < 4; ++i) MFMA_(aF[i][0], b01[0][0], acc[4 + i][0]);
#pragma unroll
        for (int i = 0; i < 4; ++i) MFMA_(aF[i][0], b01[1][0], acc[4 + i][1]);
#pragma unroll
        for (int i = 0; i < 4; ++i) MFMA_(aF[i][1], b01[0][1], acc[4 + i][0]);
#pragma unroll
        for (int i = 0; i < 4; ++i) MFMA_(aF[i][1], b01[1][1], acc[4 + i][1]);
        __builtin_amdgcn_s_setprio(0);
        PH_END_V4();

        pa0 += 128; pb0 += 128;
    }
    asm volatile("s_waitcnt vmcnt(0)" ::: "memory");   // no GLL lands after LDS is reused

    // ---------------- epilogue ----------------
    const int which = gn0 >> 11;          // 0:q 1:k 2:sq 3:sk (block-uniform)
    ss[tid] = 0.0f;
    __syncthreads();

    const int h = wn >> 1;                // head-half within the 256-wide tile (Dh=128)
    if (which < 2) {
#pragma unroll
        for (int i = 0; i < 8; ++i) {
#pragma unroll
            for (int r = 0; r < 4; ++r) {
                float sv = acc[i][0][r] * acc[i][0][r] + acc[i][1][r] * acc[i][1][r]
                         + acc[i][2][r] * acc[i][2][r] + acc[i][3][r] * acc[i][3][r];
                sv += __shfl_xor(sv, 1, 64);
                sv += __shfl_xor(sv, 2, 64);
                sv += __shfl_xor(sv, 4, 64);
                sv += __shfl_xor(sv, 8, 64);
                if ((lane & 15) == 0)
                    atomicAdd(&ss[h * 256 + wm * 128 + i * 16 + (lane >> 4) * 4 + r], sv);
            }
        }
        __syncthreads();
    }

    u16* ob = (which == 0) ? qb : (which == 1) ? kb : (which == 2) ? sqb : skb;
    const int col0 = (gn0 & 2047) + wn * 64 + (lane & 15);
#pragma unroll
    for (int i = 0; i < 8; ++i) {
#pragma unroll
        for (int r = 0; r < 4; ++r) {
            const int m = wm * 128 + i * 16 + (lane >> 4) * 4 + r;
            const size_t rowbase = (size_t)(gm0 + m) * 2048;
            float scale = 1.0f;
            if (which < 2)
                scale = rsqrtf(ss[h * 256 + m] * (1.0f / 128.0f) + 1.1920929e-07f);
#pragma unroll
            for (int j = 0; j < 4; ++j) {
                float v = acc[i][j][r];
                v = (which < 2) ? v * scale : softplus_f(v);
                ob[rowbase + col0 + j * 16] = f2bf(v);
            }
        }
    }
}

// ---------------- interp + multiply, 8 elems/thread, vectorized ----------------
__global__ void interp_mul(const u16* __restrict__ qb, const u16* __restrict__ kb,
                           const u16* __restrict__ sqb, const u16* __restrict__ skb,
                           float* __restrict__ out)
{
    size_t base = ((size_t)blockIdx.x * 256 + threadIdx.x) * 8;
    int c0 = (int)(base & 2047);
    size_t bt = base >> 11;
    int t = (int)(bt & 4095);
    float tf = (float)t;
    size_t rb = (base >> 23) << 23;   // b * T * 2048

    u16x8 sqv8 = *(const u16x8*)&sqb[base];
    u16x8 skv8 = *(const u16x8*)&skb[base];

    float o[8];
#pragma unroll
    for (int e = 0; e < 8; ++e) {
        float sqv = bf2f(sqv8[e]);
        float skv = bf2f(skv8[e]);
        float pq = fminf(fmaxf(tf - sqv, 0.0f), tf);
        float pk = fminf(fmaxf(tf - skv, 0.0f), tf);
        float pqf = floorf(pq), pkf = floorf(pk);
        int q0i = (int)pqf, k0i = (int)pkf;
        int q1i = min(q0i + 1, 4095), k1i = min(k0i + 1, 4095);
        float fq = pq - pqf, fk = pk - pkf;
        size_t oo = rb + (size_t)(c0 + e);
        float q0 = bf2f(qb[oo + ((size_t)q0i << 11)]);
        float q1 = bf2f(qb[oo + ((size_t)q1i << 11)]);
        float k0 = bf2f(kb[oo + ((size_t)k0i << 11)]);
        float k1 = bf2f(kb[oo + ((size_t)k1i << 11)]);
        float qd = q0 + (q1 - q0) * fq;
        float kd = k0 + (k1 - k0) * fk;
        o[e] = qd * kd;
    }
    float4* op = (float4*)&out[base];
    op[0] = make_float4(o[0], o[1], o[2], o[3]);
    op[1] = make_float4(o[4], o[5], o[6], o[7]);
}

extern "C" void kernel_launch(void* const* d_in, const int* in_sizes, int n_in,
                              void* d_out, int out_size, void* d_ws, size_t ws_size,
                              hipStream_t stream) {
    const float* x   = (const float*)d_in[0];
    const float* Wq  = (const float*)d_in[1];
    const float* Wk  = (const float*)d_in[2];
    const float* Wsq = (const float*)d_in[3];
    const float* Wsk = (const float*)d_in[4];
    float* out = (float*)d_out;

    // ws layout (bytes): xb 64MB | wb 32MB | qb 64MB | kb 64MB | sqb 64MB | skb 64MB = 352MB
    const size_t NEED = 369098752;
    if (ws_size < NEED) return;
    char* ws = (char*)d_ws;
    u16* xb  = (u16*)(ws);
    u16* wb  = (u16*)(ws + 67108864);
    u16* qb  = (u16*)(ws + 100663296);
    u16* kb  = (u16*)(ws + 167772160);
    u16* sqb = (u16*)(ws + 234881024);
    u16* skb = (u16*)(ws + 301989888);

    pack_kernel<<<32768, 256, 0, stream>>>(x, xb, 8388608);
    dim3 wgrid(4096, 4);
    pack4_kernel<<<wgrid, 256, 0, stream>>>(Wq, Wk, Wsq, Wsk, wb);

    dim3 ggrid(32, 64);   // N tiles x M tiles
    gemm_fused<<<ggrid, 512, 0, stream>>>(xb, wb, qb, kb, sqb, skb);

    interp_mul<<<16384, 256, 0, stream>>>(qb, kb, sqb, skb, out);
}

// Round 4
// 1305.972 us; speedup vs baseline: 1.1299x; 1.1299x over previous
//
#include <hip/hip_runtime.h>

typedef unsigned short u16;
typedef __bf16 bf16x8 __attribute__((ext_vector_type(8)));
typedef unsigned short u16x8 __attribute__((ext_vector_type(8)));
typedef unsigned short u16x4 __attribute__((ext_vector_type(4)));
typedef float f32x4 __attribute__((ext_vector_type(4)));

#define K_DIM 2048

// async global->LDS, 16B per lane; lds ptr must be wave-uniform base (+lane*16 in HW)
#define GLL16(g, l) __builtin_amdgcn_global_load_lds( \
    (const __attribute__((address_space(1))) void*)(g), \
    (__attribute__((address_space(3))) void*)(l), 16, 0, 0)

#define SB()  __builtin_amdgcn_sched_barrier(0)
#define BAR() __builtin_amdgcn_s_barrier()
// phase entry: barrier, then wait own ds_reads (issued pre-barrier), fence (rule #18)
#define PH_PRE()  do { SB(); BAR(); asm volatile("s_waitcnt lgkmcnt(0)"); SB(); } while (0)
#define PH_END()  do { SB(); BAR(); SB(); } while (0)
#define PH_END_V4() do { SB(); asm volatile("s_waitcnt vmcnt(4)"); SB(); BAR(); SB(); } while (0)
// opaque LDS read: compiler can't alias this with global_load_lds dests -> no auto vmcnt(0)
__device__ __forceinline__ u16x8 ldsr(const u16* p) {
    u16x8 r;
    asm volatile("ds_read_b128 %0, %1" : "=v"(r) : "v"((unsigned)(unsigned long long)p));
    return r;
}
#define MFMA_(av, bv, cc) (cc) = __builtin_amdgcn_mfma_f32_16x16x32_bf16( \
    __builtin_bit_cast(bf16x8, (av)), __builtin_bit_cast(bf16x8, (bv)), (cc), 0, 0, 0)

__device__ __forceinline__ u16 f2bf(float f) {
    unsigned int u = __builtin_bit_cast(unsigned int, f);
    u = (u + 0x7fffu + ((u >> 16) & 1u)) >> 16;   // RNE
    return (u16)u;
}
__device__ __forceinline__ float bf2f(u16 h) {
    unsigned int u = ((unsigned int)h) << 16;
    return __builtin_bit_cast(float, u);
}
__device__ __forceinline__ float softplus_f(float v) {
    return fmaxf(v, 0.0f) + log1pf(expf(-fabsf(v)));
}

// ---------------- pack f32 -> bf16, 4 elems/thread ----------------
__global__ void pack_kernel(const float* __restrict__ src, u16* __restrict__ dst, int n4) {
    int i = blockIdx.x * blockDim.x + threadIdx.x;
    if (i >= n4) return;
    float4 v = ((const float4*)src)[i];
    u16x4 o;
    o[0] = f2bf(v.x); o[1] = f2bf(v.y); o[2] = f2bf(v.z); o[3] = f2bf(v.w);
    ((u16x4*)dst)[i] = o;
}

// ---- pack all 4 weight matrices in one launch: grid.y selects source ----
__global__ void pack4_kernel(const float* __restrict__ s0, const float* __restrict__ s1,
                             const float* __restrict__ s2, const float* __restrict__ s3,
                             u16* __restrict__ dst) {
    int i = blockIdx.x * blockDim.x + threadIdx.x;   // 0 .. 1048575 (float4 units)
    const float* src = (blockIdx.y == 0) ? s0 : (blockIdx.y == 1) ? s1
                     : (blockIdx.y == 2) ? s2 : s3;
    float4 v = ((const float4*)src)[i];
    u16x4 o;
    o[0] = f2bf(v.x); o[1] = f2bf(v.y); o[2] = f2bf(v.z); o[3] = f2bf(v.w);
    ((u16x4*)(dst + (size_t)blockIdx.y * 4194304))[i] = o;
}

// ---------------- fused GEMM: C = A * B^T, 256x256 tile, BK=64, 8-phase counted-vmcnt ----------------
// Same schedule as R3 (hazards audited: all staged regions' last read >=1 barrier before the
// staging GLL issues; vmcnt(4) at ph4 drains buf1-A+prev-buf1-B before ph5; at ph8 drains
// buf0-B+buf0-A before next ph1). One change vs R3: all LDS fragment reads are inline-asm
// ds_read_b128 so the memory legalizer cannot tie them to the GLL queue and force vmcnt(0).
__global__ __launch_bounds__(512, 2) void gemm_fused(
    const u16* __restrict__ xb, const u16* __restrict__ wb,
    u16* __restrict__ qb, u16* __restrict__ kb,
    u16* __restrict__ sqb, u16* __restrict__ skb)
{
    __shared__ __align__(16) u16 Als[32768];   // 2 bufs x 16384 u16 (32KB each)
    __shared__ __align__(16) u16 Bls[32768];
    __shared__ float ss[512];

    const int tid  = threadIdx.x;
    const int lane = tid & 63;
    const int wave = tid >> 6;
    const int wm   = wave >> 2;     // 2 waves in M
    const int wn   = wave & 3;      // 4 waves in N
    const int gm0  = blockIdx.y * 256;
    const int gn0  = blockIdx.x * 256;

    // staging geometry (unchanged, proven correct): swizzled source chunk per lane
    const int q8 = (((lane & 3) - ((lane >> 3) & 3)) & 3) * 8;
    const int sB = wave * 512;
    const u16* pa0 = xb + (size_t)(gm0 + wave * 16 + (lane >> 2)) * K_DIM + q8;
    const u16* pb0 = wb + (size_t)(gn0 + wave * 16 + (lane >> 2)) * K_DIM + q8;
    const size_t SRC1 = (size_t)128 * K_DIM;

    // read side: lane holds row mr=lane&15 of a group, k-chunk lane>>4 at swizzled pos
    const int mr  = lane & 15;
    const int srd = ((lane >> 4) + (mr >> 1)) & 3;
    const int fro = mr * 32 + srd * 8;
    const int aRB = wm * 8 * 512 + fro;    // A groups wm*8 + i
    const int bRB = wn * 4 * 512 + fro;    // B groups wn*4 + j

    f32x4 acc[8][4] = {};

#define LDA(buf, i, ks) ldsr(&Als[(buf)*16384 + (ks)*8192 + aRB + (i)*512])
#define LDB(buf, j, ks) ldsr(&Bls[(buf)*16384 + (ks)*8192 + bRB + (j)*512])
#define STAGE_A(coff, dbase) do { \
    GLL16(pa0 + (coff),          &Als[(dbase) + sB]); \
    GLL16(pa0 + (coff) + SRC1,   &Als[(dbase) + sB + 4096]); \
    GLL16(pa0 + (coff) + 32,     &Als[(dbase) + sB + 8192]); \
    GLL16(pa0 + (coff) + SRC1 + 32, &Als[(dbase) + sB + 12288]); } while (0)
#define STAGE_B(coff, dbase) do { \
    GLL16(pb0 + (coff),          &Bls[(dbase) + sB]); \
    GLL16(pb0 + (coff) + SRC1,   &Bls[(dbase) + sB + 4096]); \
    GLL16(pb0 + (coff) + 32,     &Bls[(dbase) + sB + 8192]); \
    GLL16(pb0 + (coff) + SRC1 + 32, &Bls[(dbase) + sB + 12288]); } while (0)
#define STAGE_A_H0(coff, dbase) do { \
    GLL16(pa0 + (coff),        &Als[(dbase) + sB]); \
    GLL16(pa0 + (coff) + SRC1, &Als[(dbase) + sB + 4096]); } while (0)
#define STAGE_A_H1(coff, dbase) do { \
    GLL16(pa0 + (coff) + 32,        &Als[(dbase) + sB + 8192]); \
    GLL16(pa0 + (coff) + SRC1 + 32, &Als[(dbase) + sB + 12288]); } while (0)
#define STAGE_B_H0(coff, dbase) do { \
    GLL16(pb0 + (coff),        &Bls[(dbase) + sB]); \
    GLL16(pb0 + (coff) + SRC1, &Bls[(dbase) + sB + 4096]); } while (0)
#define STAGE_B_H1(coff, dbase) do { \
    GLL16(pb0 + (coff) + 32,        &Bls[(dbase) + sB + 8192]); \
    GLL16(pb0 + (coff) + SRC1 + 32, &Bls[(dbase) + sB + 12288]); } while (0)

    // prologue: tile0 A,B -> buf0; tile1 B -> buf1; full drain once
    STAGE_A(0, 0);
    STAGE_B(0, 0);
    STAGE_B(64, 16384);
    __syncthreads();

    for (int it = 0; it < 16; ++it) {
        u16x8 aF[4][2], b01[2][2], b23[2][2];

        // ======== ph1: a03,b01(buf0); stage A-h0 -> buf1; a03 x b01 ========
#pragma unroll
        for (int i = 0; i < 4; ++i) { aF[i][0] = LDA(0, i, 0); aF[i][1] = LDA(0, i, 1); }
#pragma unroll
        for (int j = 0; j < 2; ++j) { b01[j][0] = LDB(0, j, 0); b01[j][1] = LDB(0, j, 1); }
        STAGE_A_H0(64, 16384);
        PH_PRE();
        __builtin_amdgcn_s_setprio(1);
#pragma unroll
        for (int i = 0; i < 4; ++i) MFMA_(aF[i][0], b01[0][0], acc[i][0]);
#pragma unroll
        for (int i = 0; i < 4; ++i) MFMA_(aF[i][0], b01[1][0], acc[i][1]);
#pragma unroll
        for (int i = 0; i < 4; ++i) MFMA_(aF[i][1], b01[0][1], acc[i][0]);
#pragma unroll
        for (int i = 0; i < 4; ++i) MFMA_(aF[i][1], b01[1][1], acc[i][1]);
        __builtin_amdgcn_s_setprio(0);
        PH_END();

        // ======== ph2: b23(buf0); stage A-h1 -> buf1; a03 x b23 ========
#pragma unroll
        for (int j = 0; j < 2; ++j) { b23[j][0] = LDB(0, j + 2, 0); b23[j][1] = LDB(0, j + 2, 1); }
        STAGE_A_H1(64, 16384);
        PH_PRE();
        __builtin_amdgcn_s_setprio(1);
#pragma unroll
        for (int i = 0; i < 4; ++i) MFMA_(aF[i][0], b23[0][0], acc[i][2]);
#pragma unroll
        for (int i = 0; i < 4; ++i) MFMA_(aF[i][0], b23[1][0], acc[i][3]);
#pragma unroll
        for (int i = 0; i < 4; ++i) MFMA_(aF[i][1], b23[0][1], acc[i][2]);
#pragma unroll
        for (int i = 0; i < 4; ++i) MFMA_(aF[i][1], b23[1][1], acc[i][3]);
        __builtin_amdgcn_s_setprio(0);
        PH_END();

        // ======== ph3: a47(buf0); stage B-h0 -> buf0(next); a47 x b23 ========
#pragma unroll
        for (int i = 0; i < 4; ++i) { aF[i][0] = LDA(0, i + 4, 0); aF[i][1] = LDA(0, i + 4, 1); }
        STAGE_B_H0(128, 0);
        PH_PRE();
        __builtin_amdgcn_s_setprio(1);
#pragma unroll
        for (int i = 0; i < 4; ++i) MFMA_(aF[i][0], b23[0][0], acc[4 + i][2]);
#pragma unroll
        for (int i = 0; i < 4; ++i) MFMA_(aF[i][0], b23[1][0], acc[4 + i][3]);
#pragma unroll
        for (int i = 0; i < 4; ++i) MFMA_(aF[i][1], b23[0][1], acc[4 + i][2]);
#pragma unroll
        for (int i = 0; i < 4; ++i) MFMA_(aF[i][1], b23[1][1], acc[4 + i][3]);
        __builtin_amdgcn_s_setprio(0);
        PH_END();

        // ======== ph4: stage B-h1 -> buf0(next); a47 x b01; vmcnt(4) ========
        STAGE_B_H1(128, 0);
        PH_PRE();
        __builtin_amdgcn_s_setprio(1);
#pragma unroll
        for (int i = 0; i < 4; ++i) MFMA_(aF[i][0], b01[0][0], acc[4 + i][0]);
#pragma unroll
        for (int i = 0; i < 4; ++i) MFMA_(aF[i][0], b01[1][0], acc[4 + i][1]);
#pragma unroll
        for (int i = 0; i < 4; ++i) MFMA_(aF[i][1], b01[0][1], acc[4 + i][0]);
#pragma unroll
        for (int i = 0; i < 4; ++i) MFMA_(aF[i][1], b01[1][1], acc[4 + i][1]);
        __builtin_amdgcn_s_setprio(0);
        PH_END_V4();

        // ======== ph5: a03,b01(buf1); stage A-h0 -> buf0(next); a03 x b01 ========
#pragma unroll
        for (int i = 0; i < 4; ++i) { aF[i][0] = LDA(1, i, 0); aF[i][1] = LDA(1, i, 1); }
#pragma unroll
        for (int j = 0; j < 2; ++j) { b01[j][0] = LDB(1, j, 0); b01[j][1] = LDB(1, j, 1); }
        STAGE_A_H0(128, 0);
        PH_PRE();
        __builtin_amdgcn_s_setprio(1);
#pragma unroll
        for (int i = 0; i < 4; ++i) MFMA_(aF[i][0], b01[0][0], acc[i][0]);
#pragma unroll
        for (int i = 0; i < 4; ++i) MFMA_(aF[i][0], b01[1][0], acc[i][1]);
#pragma unroll
        for (int i = 0; i < 4; ++i) MFMA_(aF[i][1], b01[0][1], acc[i][0]);
#pragma unroll
        for (int i = 0; i < 4; ++i) MFMA_(aF[i][1], b01[1][1], acc[i][1]);
        __builtin_amdgcn_s_setprio(0);
        PH_END();

        // ======== ph6: b23(buf1); stage A-h1 -> buf0(next); a03 x b23 ========
#pragma unroll
        for (int j = 0; j < 2; ++j) { b23[j][0] = LDB(1, j + 2, 0); b23[j][1] = LDB(1, j + 2, 1); }
        STAGE_A_H1(128, 0);
        PH_PRE();
        __builtin_amdgcn_s_setprio(1);
#pragma unroll
        for (int i = 0; i < 4; ++i) MFMA_(aF[i][0], b23[0][0], acc[i][2]);
#pragma unroll
        for (int i = 0; i < 4; ++i) MFMA_(aF[i][0], b23[1][0], acc[i][3]);
#pragma unroll
        for (int i = 0; i < 4; ++i) MFMA_(aF[i][1], b23[0][1], acc[i][2]);
#pragma unroll
        for (int i = 0; i < 4; ++i) MFMA_(aF[i][1], b23[1][1], acc[i][3]);
        __builtin_amdgcn_s_setprio(0);
        PH_END();

        // ======== ph7: a47(buf1); stage B-h0 -> buf1(next); a47 x b23 ========
#pragma unroll
        for (int i = 0; i < 4; ++i) { aF[i][0] = LDA(1, i + 4, 0); aF[i][1] = LDA(1, i + 4, 1); }
        STAGE_B_H0(192, 16384);
        PH_PRE();
        __builtin_amdgcn_s_setprio(1);
#pragma unroll
        for (int i = 0; i < 4; ++i) MFMA_(aF[i][0], b23[0][0], acc[4 + i][2]);
#pragma unroll
        for (int i = 0; i < 4; ++i) MFMA_(aF[i][0], b23[1][0], acc[4 + i][3]);
#pragma unroll
        for (int i = 0; i < 4; ++i) MFMA_(aF[i][1], b23[0][1], acc[4 + i][2]);
#pragma unroll
        for (int i = 0; i < 4; ++i) MFMA_(aF[i][1], b23[1][1], acc[4 + i][3]);
        __builtin_amdgcn_s_setprio(0);
        PH_END();

        // ======== ph8: stage B-h1 -> buf1(next); a47 x b01; vmcnt(4) ========
        STAGE_B_H1(192, 16384);
        PH_PRE();
        __builtin_amdgcn_s_setprio(1);
#pragma unroll
        for (int i = 0; i < 4; ++i) MFMA_(aF[i][0], b01[0][0], acc[4 + i][0]);
#pragma unroll
        for (int i = 0; i < 4; ++i) MFMA_(aF[i][0], b01[1][0], acc[4 + i][1]);
#pragma unroll
        for (int i = 0; i < 4; ++i) MFMA_(aF[i][1], b01[0][1], acc[4 + i][0]);
#pragma unroll
        for (int i = 0; i < 4; ++i) MFMA_(aF[i][1], b01[1][1], acc[4 + i][1]);
        __builtin_amdgcn_s_setprio(0);
        PH_END_V4();

        pa0 += 128; pb0 += 128;
    }
    asm volatile("s_waitcnt vmcnt(0)" ::: "memory");   // no GLL lands after LDS is reused

    // ---------------- epilogue ----------------
    const int which = gn0 >> 11;          // 0:q 1:k 2:sq 3:sk (block-uniform)
    ss[tid] = 0.0f;
    __syncthreads();

    const int h = wn >> 1;                // head-half within the 256-wide tile (Dh=128)
    if (which < 2) {
#pragma unroll
        for (int i = 0; i < 8; ++i) {
#pragma unroll
            for (int r = 0; r < 4; ++r) {
                float sv = acc[i][0][r] * acc[i][0][r] + acc[i][1][r] * acc[i][1][r]
                         + acc[i][2][r] * acc[i][2][r] + acc[i][3][r] * acc[i][3][r];
                sv += __shfl_xor(sv, 1, 64);
                sv += __shfl_xor(sv, 2, 64);
                sv += __shfl_xor(sv, 4, 64);
                sv += __shfl_xor(sv, 8, 64);
                if ((lane & 15) == 0)
                    atomicAdd(&ss[h * 256 + wm * 128 + i * 16 + (lane >> 4) * 4 + r], sv);
            }
        }
        __syncthreads();
    }

    u16* ob = (which == 0) ? qb : (which == 1) ? kb : (which == 2) ? sqb : skb;
    const int col0 = (gn0 & 2047) + wn * 64 + (lane & 15);
#pragma unroll
    for (int i = 0; i < 8; ++i) {
#pragma unroll
        for (int r = 0; r < 4; ++r) {
            const int m = wm * 128 + i * 16 + (lane >> 4) * 4 + r;
            const size_t rowbase = (size_t)(gm0 + m) * 2048;
            float scale = 1.0f;
            if (which < 2)
                scale = rsqrtf(ss[h * 256 + m] * (1.0f / 128.0f) + 1.1920929e-07f);
#pragma unroll
            for (int j = 0; j < 4; ++j) {
                float v = acc[i][j][r];
                v = (which < 2) ? v * scale : softplus_f(v);
                ob[rowbase + col0 + j * 16] = f2bf(v);
            }
        }
    }
}

// ---------------- interp + multiply, 8 elems/thread, vectorized ----------------
__global__ void interp_mul(const u16* __restrict__ qb, const u16* __restrict__ kb,
                           const u16* __restrict__ sqb, const u16* __restrict__ skb,
                           float* __restrict__ out)
{
    size_t base = ((size_t)blockIdx.x * 256 + threadIdx.x) * 8;
    int c0 = (int)(base & 2047);
    size_t bt = base >> 11;
    int t = (int)(bt & 4095);
    float tf = (float)t;
    size_t rb = (base >> 23) << 23;   // b * T * 2048

    u16x8 sqv8 = *(const u16x8*)&sqb[base];
    u16x8 skv8 = *(const u16x8*)&skb[base];

    float o[8];
#pragma unroll
    for (int e = 0; e < 8; ++e) {
        float sqv = bf2f(sqv8[e]);
        float skv = bf2f(skv8[e]);
        float pq = fminf(fmaxf(tf - sqv, 0.0f), tf);
        float pk = fminf(fmaxf(tf - skv, 0.0f), tf);
        float pqf = floorf(pq), pkf = floorf(pk);
        int q0i = (int)pqf, k0i = (int)pkf;
        int q1i = min(q0i + 1, 4095), k1i = min(k0i + 1, 4095);
        float fq = pq - pqf, fk = pk - pkf;
        size_t oo = rb + (size_t)(c0 + e);
        float q0 = bf2f(qb[oo + ((size_t)q0i << 11)]);
        float q1 = bf2f(qb[oo + ((size_t)q1i << 11)]);
        float k0 = bf2f(kb[oo + ((size_t)k0i << 11)]);
        float k1 = bf2f(kb[oo + ((size_t)k1i << 11)]);
        float qd = q0 + (q1 - q0) * fq;
        float kd = k0 + (k1 - k0) * fk;
        o[e] = qd * kd;
    }
    float4* op = (float4*)&out[base];
    op[0] = make_float4(o[0], o[1], o[2], o[3]);
    op[1] = make_float4(o[4], o[5], o[6], o[7]);
}

extern "C" void kernel_launch(void* const* d_in, const int* in_sizes, int n_in,
                              void* d_out, int out_size, void* d_ws, size_t ws_size,
                              hipStream_t stream) {
    const float* x   = (const float*)d_in[0];
    const float* Wq  = (const float*)d_in[1];
    const float* Wk  = (const float*)d_in[2];
    const float* Wsq = (const float*)d_in[3];
    const float* Wsk = (const float*)d_in[4];
    float* out = (float*)d_out;

    // ws layout (bytes): xb 64MB | wb 32MB | qb 64MB | kb 64MB | sqb 64MB | skb 64MB = 352MB
    const size_t NEED = 369098752;
    if (ws_size < NEED) return;
    char* ws = (char*)d_ws;
    u16* xb  = (u16*)(ws);
    u16* wb  = (u16*)(ws + 67108864);
    u16* qb  = (u16*)(ws + 100663296);
    u16* kb  = (u16*)(ws + 167772160);
    u16* sqb = (u16*)(ws + 234881024);
    u16* skb = (u16*)(ws + 301989888);

    pack_kernel<<<32768, 256, 0, stream>>>(x, xb, 8388608);
    dim3 wgrid(4096, 4);
    pack4_kernel<<<wgrid, 256, 0, stream>>>(Wq, Wk, Wsq, Wsk, wb);

    dim3 ggrid(32, 64);   // N tiles x M tiles
    gemm_fused<<<ggrid, 512, 0, stream>>>(xb, wb, qb, kb, sqb, skb);

    interp_mul<<<16384, 256, 0, stream>>>(qb, kb, sqb, skb, out);
}